// Round 8
// baseline (282.252 us; speedup 1.0000x reference)
//
#include <hip/hip_runtime.h>
#include <hip/hip_bf16.h>

#define TPB 256
#define HW 4096
#define NB 4096            // 12-bit radix on key bits 30..19
#define RPB 4              // rows per persistent block

typedef unsigned int u32;
typedef unsigned long long u64;
typedef float floatx4 __attribute__((ext_vector_type(4)));  // native vec for nontemporal builtin

__global__ void __launch_bounds__(TPB, 6)
topk_blend_kernel(const float* __restrict__ x, const float* __restrict__ taup,
                  const int* __restrict__ kp, float* __restrict__ out)
{
    __shared__ u32 hist[NB];            // 16 KiB; swizzled histogram, reused as cand storage
    __shared__ u32 waveTot[4];
    __shared__ u32 sh_b, sh_k1, sh_cnt, sh_pstar;

    const int tid  = threadIdx.x;
    const int lane = tid & 63;
    const int wv   = tid >> 6;
    const int row0 = blockIdx.x * RPB;

    const u32  K   = (u32)(*kp);
    const float tau = *taup;
    const float om  = 1.0f - tau;
    const u32  xm  = (u32)(tid & 31);   // swizzle mask for this thread's chunk

    if (K >= HW) {                      // reference returns x verbatim (rare path)
        for (int i = 0; i < RPB; ++i) {
            const float4* xr = reinterpret_cast<const float4*>(x + (size_t)(row0 + i) * HW);
            float4*       ow = reinterpret_cast<float4*>(out + (size_t)(row0 + i) * HW);
#pragma unroll
            for (int j = 0; j < 4; ++j) ow[tid + j * TPB] = xr[tid + j * TPB];
        }
        return;
    }

    u32 rA[16], rB[16];
    {   // prologue: load row0 into rA
        const float4* xr = reinterpret_cast<const float4*>(x + (size_t)row0 * HW);
#pragma unroll
        for (int j = 0; j < 4; ++j) {
            float4 v = xr[tid + j * TPB];
            rA[4*j+0] = __float_as_uint(v.x); rA[4*j+1] = __float_as_uint(v.y);
            rA[4*j+2] = __float_as_uint(v.z); rA[4*j+3] = __float_as_uint(v.w);
        }
    }

    auto process = [&](u32 (&r)[16], u32 (&rn)[16], int row, int nrow) {
        // ---- prefetch next row into rn (waitcnt lands at next call's use) ----
        if (nrow >= 0) {
            const float4* xr = reinterpret_cast<const float4*>(x + (size_t)nrow * HW);
#pragma unroll
            for (int j = 0; j < 4; ++j) {
                float4 v = xr[tid + j * TPB];
                rn[4*j+0] = __float_as_uint(v.x); rn[4*j+1] = __float_as_uint(v.y);
                rn[4*j+2] = __float_as_uint(v.z); rn[4*j+3] = __float_as_uint(v.w);
            }
        }

        // ---- clear histogram (b128 stores, order-independent) ----
        uint4* h4 = reinterpret_cast<uint4*>(hist);
        const uint4 z4 = make_uint4(0u, 0u, 0u, 0u);
#pragma unroll
        for (int j = 0; j < NB / 4 / TPB; ++j) h4[tid + j * TPB] = z4;
        if (tid == 0) sh_cnt = 0;
        __syncthreads();                               // A: clear done

        // ---- histogram (swizzled bins; bijective XOR keeps counts exact) ----
#pragma unroll
        for (int e = 0; e < 16; ++e) {
            u32 bin = (r[e] & 0x7fffffffu) >> 19;
            atomicAdd(&hist[bin ^ ((bin >> 4) & 31u)], 1u);
        }
        __syncthreads();                               // B: histogram done

        // ---- parallel crossing search (conflict-free strided-by-swizzle reads) ----
        u32 hh[16];
        u32 s = 0;
#pragma unroll
        for (int j = 0; j < 16; ++j) {
            hh[j] = hist[(u32)(tid * 16 + j) ^ xm];    // == swz(tid*16+j)
            s += hh[j];
        }
        u32 suf = s;                                   // wave suffix-inclusive scan
#pragma unroll
        for (int d = 1; d < 64; d <<= 1) {
            u32 t = __shfl_down(suf, d, 64);
            if (lane + d < 64) suf += t;
        }
        if (lane == 0) waveTot[wv] = suf;
        __syncthreads();                               // C
        u32 above = suf - s;
#pragma unroll
        for (int w2 = 0; w2 < 4; ++w2)
            if (w2 > wv) above += waveTot[w2];

        if (above < K && above + s >= K) {             // exactly one thread
            u32 c = above;
            int fb = -1; u32 kk = 0;
#pragma unroll
            for (int bi = 15; bi >= 0; --bi) {
                u32 hb = hh[bi];
                if (fb < 0) {
                    if (c + hb >= K) { fb = bi; kk = K - c; }
                    else c += hb;
                }
            }
            sh_b  = (u32)(tid * 16 + fb);              // logical bin index
            sh_k1 = kk;
        }
        __syncthreads();                               // D: hist free for reuse

        const u32 bstar = sh_b;
        const u32 k1    = sh_k1;

        // ---- gather crossing-bin candidates (plain atomic: ~150 hits total) ----
        u32* cand = hist;
#pragma unroll
        for (int e = 0; e < 16; ++e) {
            u32 key = r[e] & 0x7fffffffu;
            if ((key >> 19) == bstar) {
                u32 pos = atomicAdd(&sh_cnt, 1u);
                u32 idx = (u32)((((e >> 2) * TPB + tid) << 2) | (e & 3));
                cand[pos] = ((key & 0x7ffffu) << 12) | (4095u - idx);
            }
        }
        __syncthreads();                               // E: candidates gathered

        const u32 ceq = sh_cnt;
        // ---- exact rank: k1-th largest pack (packs unique) ----
        for (u32 i = tid; i < ceq; i += TPB) {
            u32 p  = cand[i];
            u32 rk = 0;
            for (u32 j2 = 0; j2 < ceq; ++j2)
                rk += (cand[j2] > p) ? 1u : 0u;
            if (rk == k1 - 1u) sh_pstar = p;
        }
        __syncthreads();                               // F
        const u32 pstar = sh_pstar;

        // ---- epilogue: blend + nontemporal coalesced store ----
        floatx4* ow = reinterpret_cast<floatx4*>(out + (size_t)row * HW);
#pragma unroll
        for (int j = 0; j < 4; ++j) {
            floatx4 o;
#pragma unroll
            for (int l = 0; l < 4; ++l) {
                int e = 4 * j + l;
                u32 rb   = r[e];
                u32 key  = rb & 0x7fffffffu;
                u32 bin  = key >> 19;
                u32 idx  = (u32)((((j * TPB + tid) << 2) | l));
                u32 pack = ((key & 0x7ffffu) << 12) | (4095u - idx);
                bool keep = (bin > bstar) || (bin == bstar && pack >= pstar);
                float xv = __uint_as_float(rb);
                o[l] = keep ? (xv * tau + xv * om) : (xv * om);
            }
            __builtin_nontemporal_store(o, &ow[tid + j * TPB]);
        }
    };

    process(rA, rB, row0 + 0, row0 + 1);
    process(rB, rA, row0 + 1, row0 + 2);
    process(rA, rB, row0 + 2, row0 + 3);
    process(rB, rA, row0 + 3, -1);
}

extern "C" void kernel_launch(void* const* d_in, const int* in_sizes, int n_in,
                              void* d_out, int out_size, void* d_ws, size_t ws_size,
                              hipStream_t stream)
{
    (void)n_in; (void)out_size; (void)d_ws; (void)ws_size;
    const float* x   = (const float*)d_in[0];
    const float* tau = (const float*)d_in[1];
    const int*   kp  = (const int*)d_in[2];
    float*       out = (float*)d_out;
    const int nrows  = in_sizes[0] / HW;   // 32*256 = 8192 rows
    topk_blend_kernel<<<nrows / RPB, TPB, 0, stream>>>(x, tau, kp, out);
}